// Round 3
// baseline (603.167 us; speedup 1.0000x reference)
//
#include <hip/hip_runtime.h>
#include <math.h>

#define DH 128
#define BCAP 10000

typedef __bf16 bf8_t __attribute__((ext_vector_type(8)));
typedef short short8 __attribute__((ext_vector_type(8)));
typedef float f4_t __attribute__((ext_vector_type(4)));

__device__ inline unsigned short f2b(float f) {
    unsigned int u = __builtin_bit_cast(unsigned int, f);
    u = u + 0x7fffu + ((u >> 16) & 1u);  // RNE
    return (unsigned short)(u >> 16);
}
__device__ inline float b2f(unsigned short h) {
    return __builtin_bit_cast(float, (unsigned int)h << 16);
}

// ---------- degree + dinv ----------
__global__ void k_deg(const int* __restrict__ col, int* __restrict__ deg, int E) {
    int i = blockIdx.x * blockDim.x + threadIdx.x;
    if (i < E) atomicAdd(&deg[col[i]], 1);
}

__global__ void k_dinv(const int* __restrict__ deg, float* __restrict__ dinv, int N) {
    int i = blockIdx.x * blockDim.x + threadIdx.x;
    if (i < N) dinv[i] = rsqrtf((float)(deg[i] + 1));  // +1 = self loop
}

// ---------- hierarchical exclusive scan of deg -> off ----------
__global__ __launch_bounds__(256) void k_part(const int* __restrict__ deg,
                                              int* __restrict__ part, int N) {
    int b = blockIdx.x, t = threadIdx.x;
    int base = b * 1024 + t * 4;
    int s = 0;
    if (base + 3 < N) {
        int4 d = *(const int4*)&deg[base];
        s = d.x + d.y + d.z + d.w;
    } else {
        for (int i = 0; i < 4; i++) if (base + i < N) s += deg[base + i];
    }
    __shared__ int sm[256];
    sm[t] = s; __syncthreads();
    for (int d = 128; d > 0; d >>= 1) { if (t < d) sm[t] += sm[t + d]; __syncthreads(); }
    if (t == 0) part[b] = sm[0];
}

__global__ __launch_bounds__(128) void k_scanpart(const int* __restrict__ part,
                                                  int* __restrict__ poff,
                                                  int* __restrict__ off, int nb, int N) {
    __shared__ int sm[128];
    int t = threadIdx.x;
    sm[t] = (t < nb) ? part[t] : 0;
    __syncthreads();
    for (int d = 1; d < 128; d <<= 1) {
        int v = (t >= d) ? sm[t - d] : 0;
        __syncthreads();
        sm[t] += v;
        __syncthreads();
    }
    poff[t] = (t == 0) ? 0 : sm[t - 1];
    if (t == 127) off[N] = sm[127];
}

__global__ __launch_bounds__(256) void k_off(const int* __restrict__ deg,
                                             const int* __restrict__ poff,
                                             int* __restrict__ off, int N) {
    int b = blockIdx.x, t = threadIdx.x;
    int base = b * 1024 + t * 4;
    int d0 = 0, d1 = 0, d2 = 0, d3 = 0;
    if (base + 3 < N) {
        int4 d = *(const int4*)&deg[base];
        d0 = d.x; d1 = d.y; d2 = d.z; d3 = d.w;
    } else {
        if (base < N) d0 = deg[base];
        if (base + 1 < N) d1 = deg[base + 1];
        if (base + 2 < N) d2 = deg[base + 2];
        if (base + 3 < N) d3 = deg[base + 3];
    }
    int tot = d0 + d1 + d2 + d3;
    __shared__ int sm[256];
    sm[t] = tot; __syncthreads();
    for (int d = 1; d < 256; d <<= 1) {
        int v = (t >= d) ? sm[t - d] : 0;
        __syncthreads();
        sm[t] += v;
        __syncthreads();
    }
    int pre = poff[b] + ((t == 0) ? 0 : sm[t - 1]);
    if (base < N)     off[base] = pre;
    if (base + 1 < N) off[base + 1] = pre + d0;
    if (base + 2 < N) off[base + 2] = pre + d0 + d1;
    if (base + 3 < N) off[base + 3] = pre + d0 + d1 + d2;
}

// ---------- bucketed CSR fill ----------
// Pass A: bucket edges by dst>>9 into slack-padded regions, packed u32 = src<<9 | (dst&511).
__global__ __launch_bounds__(256) void k_bucket(const int* __restrict__ row,
                                                const int* __restrict__ col,
                                                int E, int nbuck, int chunk,
                                                unsigned int* __restrict__ pairs,
                                                int* __restrict__ bcur,
                                                int2* __restrict__ ovf,
                                                int* __restrict__ ovfcnt) {
    __shared__ int lcnt[256];
    __shared__ int lbase[256];
    int t = threadIdx.x;
    int e0 = blockIdx.x * chunk;
    int e1 = min(e0 + chunk, E);
    lcnt[t] = 0;
    __syncthreads();
    for (int i = e0 + t; i < e1; i += 256)
        atomicAdd(&lcnt[col[i] >> 9], 1);
    __syncthreads();
    if (t < nbuck) {
        int c = lcnt[t];
        if (c > 0) lbase[t] = atomicAdd(&bcur[t], c);
    }
    __syncthreads();
    lcnt[t] = 0;
    __syncthreads();
    for (int i = e0 + t; i < e1; i += 256) {
        int d = col[i];
        int b = d >> 9;
        int p = atomicAdd(&lcnt[b], 1);
        int slot = lbase[b] + p;
        if (slot < BCAP) {
            pairs[(size_t)b * BCAP + slot] =
                ((unsigned int)row[i] << 9) | (unsigned int)(d & 511);
        } else {
            int o = atomicAdd(ovfcnt, 1);
            ovf[o] = make_int2(row[i], d);
        }
    }
}

// Pass B: per-bucket fine scatter into the bucket's ~32KB csr window (L2-local).
__global__ __launch_bounds__(256) void k_fill2(const unsigned int* __restrict__ pairs,
                                               const int* __restrict__ bcur,
                                               int nbuck, int S,
                                               const int* __restrict__ off,
                                               int* __restrict__ cur,
                                               int* __restrict__ csr,
                                               const int2* __restrict__ ovf,
                                               const int* __restrict__ ovfcnt) {
    int blk = blockIdx.x;
    int t = threadIdx.x;
    if (blk == nbuck * S) {  // overflow entries (normally none)
        int n = *ovfcnt;
        for (int i = t; i < n; i += 256) {
            int2 e = ovf[i];
            int p = atomicAdd(&cur[e.y], 1);
            csr[off[e.y] + p] = e.x;
        }
        return;
    }
    int b = blk / S, s = blk % S;
    int cnt = min(bcur[b], BCAP);
    int per = (cnt + S - 1) / S;
    int i0 = s * per, i1 = min(i0 + per, cnt);
    int node0 = b << 9;
    for (int i = i0 + t; i < i1; i += 256) {
        unsigned int v = pairs[(size_t)b * BCAP + i];
        int src = (int)(v >> 9);
        int d = node0 + (int)(v & 511u);
        int p = atomicAdd(&cur[d], 1);
        csr[off[d] + p] = src;
    }
}

// ---------- W prep: Wt[n][k] = bf16(W[k][n]) ----------
__global__ void k_prepW(const float* __restrict__ W, unsigned short* __restrict__ Wt) {
    int t = blockIdx.x * blockDim.x + threadIdx.x;  // 16384
    int k = t >> 7, n = t & 127;
    Wt[n * DH + k] = f2b(W[k * DH + n]);
}

// ---------- MFMA GEMM: Y[r][c] = bf16( (X[r]@W)[c] * dinv[r] ) ----------
__global__ __launch_bounds__(256) void k_gemm_mfma(const void* __restrict__ Xin, int x_is_bf16,
                                                   const unsigned short* __restrict__ Wt,
                                                   const float* __restrict__ dinv,
                                                   unsigned short* __restrict__ Y, int nrows) {
    __shared__ unsigned short Xs[64 * 136];
    __shared__ unsigned short Ws[128 * 136];
    int t = threadIdx.x;
    int row0 = blockIdx.x * 64;

    for (int v = t; v < 128 * 32; v += 256) {
        int n = v >> 5, kq = v & 31;
        ushort4 w = ((const ushort4*)Wt)[v];
        *(ushort4*)&Ws[n * 136 + kq * 4] = w;
    }
    if (x_is_bf16) {
        const unsigned short* X = (const unsigned short*)Xin;
        for (int v = t; v < 64 * 32; v += 256) {
            int r = v >> 5, cq = v & 31;
            int gr = row0 + r;
            ushort4 h;
            if (gr < nrows) h = ((const ushort4*)X)[(size_t)gr * 32 + cq];
            else { h.x = 0; h.y = 0; h.z = 0; h.w = 0; }
            *(ushort4*)&Xs[r * 136 + cq * 4] = h;
        }
    } else {
        const float* X = (const float*)Xin;
        for (int v = t; v < 64 * 32; v += 256) {
            int r = v >> 5, cq = v & 31;
            int gr = row0 + r;
            ushort4 h;
            if (gr < nrows) {
                float4 xv = ((const float4*)X)[(size_t)gr * 32 + cq];
                h.x = f2b(xv.x); h.y = f2b(xv.y); h.z = f2b(xv.z); h.w = f2b(xv.w);
            } else { h.x = 0; h.y = 0; h.z = 0; h.w = 0; }
            *(ushort4*)&Xs[r * 136 + cq * 4] = h;
        }
    }
    __syncthreads();

    int w = t >> 6;
    int lane = t & 63;
    int quad = lane >> 4;
    int l16 = lane & 15;
    int rw = w * 16;

    f4_t acc[8];
#pragma unroll
    for (int j = 0; j < 8; j++) acc[j] = (f4_t){0.f, 0.f, 0.f, 0.f};

#pragma unroll
    for (int kk = 0; kk < 4; kk++) {
        int k0 = kk * 32;
        bf8_t a = __builtin_bit_cast(bf8_t,
            *(const short8*)&Xs[(rw + l16) * 136 + k0 + quad * 8]);
#pragma unroll
        for (int j = 0; j < 8; j++) {
            bf8_t b = __builtin_bit_cast(bf8_t,
                *(const short8*)&Ws[(j * 16 + l16) * 136 + k0 + quad * 8]);
            acc[j] = __builtin_amdgcn_mfma_f32_16x16x32_bf16(a, b, acc[j], 0, 0, 0);
        }
    }

#pragma unroll
    for (int reg = 0; reg < 4; reg++) {
        int r = row0 + rw + quad * 4 + reg;
        if (r < nrows) {
            float dv = dinv[r];
#pragma unroll
            for (int j = 0; j < 8; j++) {
                float val = acc[j][reg] * dv;
                Y[(size_t)r * DH + j * 16 + l16] = f2b(val);
            }
        }
    }
}

// ---------- Aggregation (pull, bf16 rows, 4 groups x 8-deep gather streams) ----------
__global__ __launch_bounds__(128) void k_agg(const unsigned short* __restrict__ Hs,
                                             void* __restrict__ Out, int out_bf16,
                                             const float* __restrict__ dinv,
                                             const int* __restrict__ off,
                                             const int* __restrict__ csr,
                                             const float* __restrict__ bias, int elu) {
    int n = blockIdx.x;
    int t = threadIdx.x;
    int g = t >> 5;   // group 0..3
    int l = t & 31;   // lane in group; 4 cols each
    int s = off[n], e = off[n + 1];
    const ushort4* rows = (const ushort4*)Hs;

    float a0 = 0.f, a1 = 0.f, a2 = 0.f, a3 = 0.f;
    if (g == 0) {  // self loop
        ushort4 v = rows[(size_t)n * 32 + l];
        a0 += b2f(v.x); a1 += b2f(v.y); a2 += b2f(v.z); a3 += b2f(v.w);
    }
    int i = s + g;
    for (; i + 28 < e; i += 32) {  // 8 independent gather streams per group
        int j0 = csr[i],      j1 = csr[i + 4],  j2 = csr[i + 8],  j3 = csr[i + 12];
        int j4 = csr[i + 16], j5 = csr[i + 20], j6 = csr[i + 24], j7 = csr[i + 28];
        ushort4 v0 = rows[(size_t)j0 * 32 + l];
        ushort4 v1 = rows[(size_t)j1 * 32 + l];
        ushort4 v2 = rows[(size_t)j2 * 32 + l];
        ushort4 v3 = rows[(size_t)j3 * 32 + l];
        ushort4 v4 = rows[(size_t)j4 * 32 + l];
        ushort4 v5 = rows[(size_t)j5 * 32 + l];
        ushort4 v6 = rows[(size_t)j6 * 32 + l];
        ushort4 v7 = rows[(size_t)j7 * 32 + l];
        a0 += b2f(v0.x) + b2f(v1.x) + b2f(v2.x) + b2f(v3.x)
            + b2f(v4.x) + b2f(v5.x) + b2f(v6.x) + b2f(v7.x);
        a1 += b2f(v0.y) + b2f(v1.y) + b2f(v2.y) + b2f(v3.y)
            + b2f(v4.y) + b2f(v5.y) + b2f(v6.y) + b2f(v7.y);
        a2 += b2f(v0.z) + b2f(v1.z) + b2f(v2.z) + b2f(v3.z)
            + b2f(v4.z) + b2f(v5.z) + b2f(v6.z) + b2f(v7.z);
        a3 += b2f(v0.w) + b2f(v1.w) + b2f(v2.w) + b2f(v3.w)
            + b2f(v4.w) + b2f(v5.w) + b2f(v6.w) + b2f(v7.w);
    }
    for (; i < e; i += 4) {
        int j = csr[i];
        ushort4 v = rows[(size_t)j * 32 + l];
        a0 += b2f(v.x); a1 += b2f(v.y); a2 += b2f(v.z); a3 += b2f(v.w);
    }

    __shared__ float ps[4 * DH];
    ps[g * DH + l * 4 + 0] = a0;
    ps[g * DH + l * 4 + 1] = a1;
    ps[g * DH + l * 4 + 2] = a2;
    ps[g * DH + l * 4 + 3] = a3;
    __syncthreads();

    float v = ps[t] + ps[DH + t] + ps[2 * DH + t] + ps[3 * DH + t];
    v = v * dinv[n] + bias[t];
    if (elu) v = v > 0.f ? v : expm1f(v);
    if (out_bf16) ((unsigned short*)Out)[(size_t)n * DH + t] = f2b(v);
    else          ((float*)Out)[(size_t)n * DH + t] = v;
}

// ---------- Mean pool (batch sorted) ----------
__global__ void k_pool(const float* __restrict__ H, const int* __restrict__ batch,
                       float* __restrict__ Gsum, int* __restrict__ cnts, int N) {
    int g = blockIdx.x;
    int p = blockIdx.y;
    int c = threadIdx.x;  // 128
    int lo = 0, hi = N;
    while (lo < hi) { int m = (lo + hi) >> 1; if (batch[m] < g) lo = m + 1; else hi = m; }
    int s = lo;
    hi = N;
    while (lo < hi) { int m = (lo + hi) >> 1; if (batch[m] < g + 1) lo = m + 1; else hi = m; }
    int e = lo;
    int len = e - s;
    int parts = (int)gridDim.y;
    int chunk = (len + parts - 1) / parts;
    int i0 = s + p * chunk;
    int i1 = min(i0 + chunk, e);
    float acc = 0.f;
    for (int i = i0; i < i1; i++) acc += H[(size_t)i * DH + c];
    atomicAdd(&Gsum[g * DH + c], acc);
    if (p == 0 && c == 0) cnts[g] = len;
}

// ---------- MLP head + log_softmax ----------
__global__ __launch_bounds__(64) void k_head(const float* __restrict__ Gsum,
                                             const int* __restrict__ cnts,
                                             const float* __restrict__ W1,
                                             const float* __restrict__ b1,
                                             const float* __restrict__ W2,
                                             const float* __restrict__ b2,
                                             float* __restrict__ out) {
    int g = blockIdx.x;
    int t = threadIdx.x;
    __shared__ float gv[DH];
    __shared__ float mid[20];
    __shared__ float o[10];
    float inv = 1.f / fmaxf((float)cnts[g], 1.f);
    for (int i = t; i < DH; i += 64) gv[i] = Gsum[g * DH + i] * inv;
    __syncthreads();
    if (t < 20) {
        float a = b1[t];
        for (int k = 0; k < DH; k++) a += gv[k] * W1[k * 20 + t];
        mid[t] = fmaxf(a, 0.f);
    }
    __syncthreads();
    if (t < 10) {
        float a = b2[t];
        for (int k = 0; k < 20; k++) a += mid[k] * W2[k * 10 + t];
        o[t] = a;
    }
    __syncthreads();
    if (t == 0) {
        float m = -1e30f;
        for (int j = 0; j < 10; j++) m = fmaxf(m, o[j]);
        float ssum = 0.f;
        for (int j = 0; j < 10; j++) ssum += expf(o[j] - m);
        float l = logf(ssum);
        for (int j = 0; j < 10; j++) out[g * 10 + j] = o[j] - m - l;
    }
}

extern "C" void kernel_launch(void* const* d_in, const int* in_sizes, int n_in,
                              void* d_out, int out_size, void* d_ws, size_t ws_size,
                              hipStream_t stream) {
    const float* x    = (const float*)d_in[0];
    const int*   ei   = (const int*)d_in[1];
    const int*   batch= (const int*)d_in[2];
    const float* W1   = (const float*)d_in[3];
    const float* b1   = (const float*)d_in[4];
    const float* W2   = (const float*)d_in[5];
    const float* b2   = (const float*)d_in[6];
    const float* fc1W = (const float*)d_in[7];
    const float* fc1b = (const float*)d_in[8];
    const float* fc2W = (const float*)d_in[9];
    const float* fc2b = (const float*)d_in[10];
    float* out = (float*)d_out;

    int N = in_sizes[0] / DH;     // 100000
    int E = in_sizes[1] / 2;      // 1600000
    int G = out_size / 10;        // 64

    char* p = (char*)d_ws;
    auto alloc = [&](size_t bytes) {
        char* r = p;
        p += (bytes + 255) & ~(size_t)255;
        return r;
    };
    unsigned short* hs = (unsigned short*)alloc((size_t)N * DH * 2);
    char* P1 = (char*)alloc((size_t)N * DH * 4);
    unsigned short* a1 = (unsigned short*)P1;  // bf16, first half
    float* a2 = (float*)P1;                    // fp32, full
    int*   csr  = (int*)alloc((size_t)E * 4);
    int*   deg  = (int*)alloc((size_t)N * 4);
    int*   off  = (int*)alloc((size_t)(N + 1) * 4);
    int*   cur  = (int*)alloc((size_t)N * 4);
    float* dinv = (float*)alloc((size_t)N * 4);
    int*   part = (int*)alloc(1024);
    int*   poff = (int*)alloc(1024);
    unsigned short* Wt1 = (unsigned short*)alloc(DH * DH * 2);
    unsigned short* Wt2 = (unsigned short*)alloc(DH * DH * 2);
    float* Gsum = (float*)alloc((size_t)G * DH * 4);
    int*   cnts = (int*)alloc((size_t)G * 4);

    int nbuck = (N + 511) >> 9;   // 196
    unsigned int* pairs = (unsigned int*)alloc((size_t)nbuck * BCAP * 4);
    int* bcur   = (int*)alloc(256 * 4);
    int2* ovf   = (int2*)alloc((size_t)65536 * 8);
    int* ovfcnt = (int*)alloc(256);

    const int* row = ei;       // message source
    const int* col = ei + E;   // aggregation target

    hipMemsetAsync(deg, 0, (size_t)N * 4, stream);
    hipMemsetAsync(cur, 0, (size_t)N * 4, stream);
    hipMemsetAsync(bcur, 0, 256 * 4, stream);
    hipMemsetAsync(ovfcnt, 0, 256, stream);
    hipMemsetAsync(Gsum, 0, (size_t)G * DH * 4, stream);

    const int tb = 256;
    int nb = (N + 1023) / 1024;  // 98
    k_deg<<<(E + tb - 1) / tb, tb, 0, stream>>>(col, deg, E);
    k_dinv<<<(N + tb - 1) / tb, tb, 0, stream>>>(deg, dinv, N);
    k_part<<<nb, 256, 0, stream>>>(deg, part, N);
    k_scanpart<<<1, 128, 0, stream>>>(part, poff, off, nb, N);
    k_off<<<nb, 256, 0, stream>>>(deg, poff, off, N);

    const int chunk = 2048;
    int ablocks = (E + chunk - 1) / chunk;  // 782
    k_bucket<<<ablocks, 256, 0, stream>>>(row, col, E, nbuck, chunk,
                                          pairs, bcur, ovf, ovfcnt);
    const int S = 8;
    k_fill2<<<nbuck * S + 1, 256, 0, stream>>>(pairs, bcur, nbuck, S,
                                               off, cur, csr, ovf, ovfcnt);

    k_prepW<<<64, 256, 0, stream>>>(W1, Wt1);
    k_prepW<<<64, 256, 0, stream>>>(W2, Wt2);

    int gblocks = (N + 63) / 64;
    // layer 1
    k_gemm_mfma<<<gblocks, 256, 0, stream>>>(x, 0, Wt1, dinv, hs, N);
    k_agg<<<N, 128, 0, stream>>>(hs, a1, 1, dinv, off, csr, b1, 1);
    // layer 2
    k_gemm_mfma<<<gblocks, 256, 0, stream>>>(a1, 1, Wt2, dinv, hs, N);
    k_agg<<<N, 128, 0, stream>>>(hs, a2, 0, dinv, off, csr, b2, 0);

    dim3 pg(G, 8);
    k_pool<<<pg, DH, 0, stream>>>(a2, batch, Gsum, cnts, N);
    k_head<<<G, 64, 0, stream>>>(Gsum, cnts, fc1W, fc1b, fc2W, fc2b, out);
}

// Round 4
// 408.292 us; speedup vs baseline: 1.4773x; 1.4773x over previous
//
#include <hip/hip_runtime.h>
#include <math.h>

#define DH 128
#define BCAP 16384  // slots per 512-node bucket (mean ~8163, >20 sigma headroom)

typedef __bf16 bf8_t __attribute__((ext_vector_type(8)));
typedef short short8 __attribute__((ext_vector_type(8)));
typedef float f4_t __attribute__((ext_vector_type(4)));

__device__ inline unsigned short f2b(float f) {
    unsigned int u = __builtin_bit_cast(unsigned int, f);
    u = u + 0x7fffu + ((u >> 16) & 1u);  // RNE
    return (unsigned short)(u >> 16);
}
__device__ inline float b2f(unsigned short h) {
    return __builtin_bit_cast(float, (unsigned int)h << 16);
}

// ---------- Pass A: bucket edges by dst>>9 ----------
// chunk<=8192 edges/block. LDS count+slot records, one line-padded global
// reservation atomic per (block,bucket). pairs u32 = src<<9 | (dst&511).
__global__ __launch_bounds__(256) void k_bucket(const int* __restrict__ row,
                                                const int* __restrict__ col,
                                                int E, int nbuck, int chunk,
                                                unsigned int* __restrict__ pairs,
                                                int* __restrict__ bcur) {
    __shared__ int lcnt[256];
    __shared__ int lbase[256];
    __shared__ unsigned int srec[8192];
    int t = threadIdx.x;
    int e0 = blockIdx.x * chunk;
    int e1 = min(e0 + chunk, E);
    lcnt[t] = 0;
    __syncthreads();
    for (int i = e0 + t; i < e1; i += 256) {
        int d = col[i];
        int b = d >> 9;
        int slot = atomicAdd(&lcnt[b], 1);
        // b:8b | dlow:9b | slot:13b
        srec[i - e0] = ((unsigned int)b << 22) | ((unsigned int)(d & 511) << 13)
                     | (unsigned int)slot;
    }
    __syncthreads();
    if (t < nbuck) {
        int c = lcnt[t];
        lbase[t] = (c > 0) ? atomicAdd(&bcur[t * 16], c) : 0;  // stride 16: 1 line/counter
    }
    __syncthreads();
    for (int i = e0 + t; i < e1; i += 256) {
        unsigned int r = srec[i - e0];
        int b = r >> 22;
        unsigned int dl = (r >> 13) & 511u;
        int slot = (int)(r & 8191u);
        int g = lbase[b] + slot;
        if (g < BCAP)
            pairs[(size_t)b * BCAP + g] = ((unsigned int)row[i] << 9) | dl;
    }
}

// ---------- Pass B: one block per bucket builds off/dinv/csr (all LDS-local) ----------
__global__ __launch_bounds__(256) void k_build(const unsigned int* __restrict__ pairs,
                                               const int* __restrict__ bcur,
                                               int nbuck, int N,
                                               int* __restrict__ off,
                                               float* __restrict__ dinv,
                                               int* __restrict__ csr) {
    __shared__ int sb[256];
    __shared__ int cnt2[512];
    __shared__ int excl[512];
    __shared__ int curi[512];
    __shared__ int stmp[256];
    int b = blockIdx.x, t = threadIdx.x;
    // scan bucket totals -> base offset of this bucket
    sb[t] = (t < nbuck) ? min(bcur[t * 16], BCAP) : 0;
    __syncthreads();
    for (int d = 1; d < 256; d <<= 1) {
        int v = (t >= d) ? sb[t - d] : 0;
        __syncthreads();
        sb[t] += v;
        __syncthreads();
    }
    int base = (b == 0) ? 0 : sb[b - 1];
    int cnt = sb[b] - base;
    int node0 = b << 9;
    int nodes = min(512, N - node0);
    cnt2[t] = 0; cnt2[t + 256] = 0;
    __syncthreads();
    const unsigned int* pp = pairs + (size_t)b * BCAP;
    for (int i = t; i < cnt; i += 256)
        atomicAdd(&cnt2[pp[i] & 511u], 1);
    __syncthreads();
    // exclusive scan of cnt2[512]
    stmp[t] = cnt2[2 * t] + cnt2[2 * t + 1];
    __syncthreads();
    for (int d = 1; d < 256; d <<= 1) {
        int v = (t >= d) ? stmp[t - d] : 0;
        __syncthreads();
        stmp[t] += v;
        __syncthreads();
    }
    int pre = (t == 0) ? 0 : stmp[t - 1];
    excl[2 * t] = pre;
    excl[2 * t + 1] = pre + cnt2[2 * t];
    __syncthreads();
    if (t < nodes) {
        off[node0 + t] = base + excl[t];
        dinv[node0 + t] = rsqrtf((float)(cnt2[t] + 1));
    }
    int t2 = t + 256;
    if (t2 < nodes) {
        off[node0 + t2] = base + excl[t2];
        dinv[node0 + t2] = rsqrtf((float)(cnt2[t2] + 1));
    }
    if (t == 0) off[node0 + nodes] = base + cnt;  // next base / off[N] for last bucket
    curi[t] = excl[t]; curi[t + 256] = excl[t + 256];
    __syncthreads();
    // scatter into this bucket's private csr window (~32KB, single XCD)
    for (int i = t; i < cnt; i += 256) {
        unsigned int p = pp[i];
        int d = (int)(p & 511u);
        int slot = atomicAdd(&curi[d], 1);
        csr[base + slot] = (int)(p >> 9);
    }
}

// ---------- W prep (both layers): Wt[n][k] = bf16(W[k][n]) ----------
__global__ void k_prepW(const float* __restrict__ W1, const float* __restrict__ W2,
                        unsigned short* __restrict__ Wt1, unsigned short* __restrict__ Wt2) {
    int t = blockIdx.x * blockDim.x + threadIdx.x;  // 32768
    const float* W = (t < 16384) ? W1 : W2;
    unsigned short* Wt = (t < 16384) ? Wt1 : Wt2;
    int v = t & 16383;
    int k = v >> 7, n = v & 127;
    Wt[n * DH + k] = f2b(W[k * DH + n]);
}

// ---------- MFMA GEMM: Y[r][c] = bf16( (X[r]@W)[c] * dinv[r] ) ----------
__global__ __launch_bounds__(256) void k_gemm_mfma(const void* __restrict__ Xin, int x_is_bf16,
                                                   const unsigned short* __restrict__ Wt,
                                                   const float* __restrict__ dinv,
                                                   unsigned short* __restrict__ Y, int nrows) {
    __shared__ unsigned short Xs[64 * 136];
    __shared__ unsigned short Ws[128 * 136];
    int t = threadIdx.x;
    int row0 = blockIdx.x * 64;

    for (int v = t; v < 128 * 32; v += 256) {
        int n = v >> 5, kq = v & 31;
        ushort4 w = ((const ushort4*)Wt)[v];
        *(ushort4*)&Ws[n * 136 + kq * 4] = w;
    }
    if (x_is_bf16) {
        const unsigned short* X = (const unsigned short*)Xin;
        for (int v = t; v < 64 * 32; v += 256) {
            int r = v >> 5, cq = v & 31;
            int gr = row0 + r;
            ushort4 h;
            if (gr < nrows) h = ((const ushort4*)X)[(size_t)gr * 32 + cq];
            else { h.x = 0; h.y = 0; h.z = 0; h.w = 0; }
            *(ushort4*)&Xs[r * 136 + cq * 4] = h;
        }
    } else {
        const float* X = (const float*)Xin;
        for (int v = t; v < 64 * 32; v += 256) {
            int r = v >> 5, cq = v & 31;
            int gr = row0 + r;
            ushort4 h;
            if (gr < nrows) {
                float4 xv = ((const float4*)X)[(size_t)gr * 32 + cq];
                h.x = f2b(xv.x); h.y = f2b(xv.y); h.z = f2b(xv.z); h.w = f2b(xv.w);
            } else { h.x = 0; h.y = 0; h.z = 0; h.w = 0; }
            *(ushort4*)&Xs[r * 136 + cq * 4] = h;
        }
    }
    __syncthreads();

    int w = t >> 6;
    int lane = t & 63;
    int quad = lane >> 4;
    int l16 = lane & 15;
    int rw = w * 16;

    f4_t acc[8];
#pragma unroll
    for (int j = 0; j < 8; j++) acc[j] = (f4_t){0.f, 0.f, 0.f, 0.f};

#pragma unroll
    for (int kk = 0; kk < 4; kk++) {
        int k0 = kk * 32;
        bf8_t a = __builtin_bit_cast(bf8_t,
            *(const short8*)&Xs[(rw + l16) * 136 + k0 + quad * 8]);
#pragma unroll
        for (int j = 0; j < 8; j++) {
            bf8_t b = __builtin_bit_cast(bf8_t,
                *(const short8*)&Ws[(j * 16 + l16) * 136 + k0 + quad * 8]);
            acc[j] = __builtin_amdgcn_mfma_f32_16x16x32_bf16(a, b, acc[j], 0, 0, 0);
        }
    }

#pragma unroll
    for (int reg = 0; reg < 4; reg++) {
        int r = row0 + rw + quad * 4 + reg;
        if (r < nrows) {
            float dv = dinv[r];
#pragma unroll
            for (int j = 0; j < 8; j++) {
                float val = acc[j][reg] * dv;
                Y[(size_t)r * DH + j * 16 + l16] = f2b(val);
            }
        }
    }
}

// ---------- Aggregation: wave-per-node, full-row u32 gathers, 8-deep MLP ----------
// out[n] = act( dinv[n]*(sum_src Hs[src] + Hs[n]) + b ), Hs rows pre-scaled.
__global__ __launch_bounds__(256) void k_agg(const unsigned int* __restrict__ Hs32,
                                             unsigned int* __restrict__ Out32,
                                             const float* __restrict__ dinv,
                                             const int* __restrict__ off,
                                             const int* __restrict__ csr,
                                             const float* __restrict__ bias,
                                             int elu, int N) {
    int wv = __builtin_amdgcn_readfirstlane((int)(threadIdx.x >> 6));
    int n = blockIdx.x * 4 + wv;
    if (n >= N) return;
    int l = threadIdx.x & 63;
    int s = off[n], e = off[n + 1];
    unsigned int u = Hs32[(size_t)n * 64 + l];  // self loop
    float a0 = b2f((unsigned short)(u & 0xffffu));
    float a1 = b2f((unsigned short)(u >> 16));
    int i = s;
    while (i + 8 <= e) {
        int j0 = csr[i], j1 = csr[i + 1], j2 = csr[i + 2], j3 = csr[i + 3];
        int j4 = csr[i + 4], j5 = csr[i + 5], j6 = csr[i + 6], j7 = csr[i + 7];
        unsigned int v0 = Hs32[(size_t)j0 * 64 + l];
        unsigned int v1 = Hs32[(size_t)j1 * 64 + l];
        unsigned int v2 = Hs32[(size_t)j2 * 64 + l];
        unsigned int v3 = Hs32[(size_t)j3 * 64 + l];
        unsigned int v4 = Hs32[(size_t)j4 * 64 + l];
        unsigned int v5 = Hs32[(size_t)j5 * 64 + l];
        unsigned int v6 = Hs32[(size_t)j6 * 64 + l];
        unsigned int v7 = Hs32[(size_t)j7 * 64 + l];
        a0 += b2f((unsigned short)(v0 & 0xffffu)) + b2f((unsigned short)(v1 & 0xffffu))
            + b2f((unsigned short)(v2 & 0xffffu)) + b2f((unsigned short)(v3 & 0xffffu))
            + b2f((unsigned short)(v4 & 0xffffu)) + b2f((unsigned short)(v5 & 0xffffu))
            + b2f((unsigned short)(v6 & 0xffffu)) + b2f((unsigned short)(v7 & 0xffffu));
        a1 += b2f((unsigned short)(v0 >> 16)) + b2f((unsigned short)(v1 >> 16))
            + b2f((unsigned short)(v2 >> 16)) + b2f((unsigned short)(v3 >> 16))
            + b2f((unsigned short)(v4 >> 16)) + b2f((unsigned short)(v5 >> 16))
            + b2f((unsigned short)(v6 >> 16)) + b2f((unsigned short)(v7 >> 16));
        i += 8;
    }
    for (; i < e; i++) {
        int j = csr[i];
        unsigned int v = Hs32[(size_t)j * 64 + l];
        a0 += b2f((unsigned short)(v & 0xffffu));
        a1 += b2f((unsigned short)(v >> 16));
    }
    float2 bb = ((const float2*)bias)[l];
    float dv = dinv[n];
    float o0 = a0 * dv + bb.x;
    float o1 = a1 * dv + bb.y;
    if (elu) {
        o0 = o0 > 0.f ? o0 : expm1f(o0);
        o1 = o1 > 0.f ? o1 : expm1f(o1);
    }
    Out32[(size_t)n * 64 + l] = (unsigned int)f2b(o0) | ((unsigned int)f2b(o1) << 16);
}

// ---------- Mean pool (batch sorted, bf16 input) ----------
__global__ void k_pool(const unsigned short* __restrict__ H, const int* __restrict__ batch,
                       float* __restrict__ Gsum, int* __restrict__ cnts, int N) {
    int g = blockIdx.x;
    int p = blockIdx.y;
    int c = threadIdx.x;  // 128
    int lo = 0, hi = N;
    while (lo < hi) { int m = (lo + hi) >> 1; if (batch[m] < g) lo = m + 1; else hi = m; }
    int s = lo;
    hi = N;
    while (lo < hi) { int m = (lo + hi) >> 1; if (batch[m] < g + 1) lo = m + 1; else hi = m; }
    int e = lo;
    int len = e - s;
    int parts = (int)gridDim.y;
    int chunk = (len + parts - 1) / parts;
    int i0 = s + p * chunk;
    int i1 = min(i0 + chunk, e);
    float acc = 0.f;
    for (int i = i0; i < i1; i++) acc += b2f(H[(size_t)i * DH + c]);
    atomicAdd(&Gsum[g * DH + c], acc);
    if (p == 0 && c == 0) cnts[g] = len;
}

// ---------- MLP head + log_softmax ----------
__global__ __launch_bounds__(64) void k_head(const float* __restrict__ Gsum,
                                             const int* __restrict__ cnts,
                                             const float* __restrict__ W1,
                                             const float* __restrict__ b1,
                                             const float* __restrict__ W2,
                                             const float* __restrict__ b2,
                                             float* __restrict__ out) {
    int g = blockIdx.x;
    int t = threadIdx.x;
    __shared__ float gv[DH];
    __shared__ float mid[20];
    __shared__ float o[10];
    float inv = 1.f / fmaxf((float)cnts[g], 1.f);
    for (int i = t; i < DH; i += 64) gv[i] = Gsum[g * DH + i] * inv;
    __syncthreads();
    if (t < 20) {
        float a = b1[t];
        for (int k = 0; k < DH; k++) a += gv[k] * W1[k * 20 + t];
        mid[t] = fmaxf(a, 0.f);
    }
    __syncthreads();
    if (t < 10) {
        float a = b2[t];
        for (int k = 0; k < 20; k++) a += mid[k] * W2[k * 10 + t];
        o[t] = a;
    }
    __syncthreads();
    if (t == 0) {
        float m = -1e30f;
        for (int j = 0; j < 10; j++) m = fmaxf(m, o[j]);
        float ssum = 0.f;
        for (int j = 0; j < 10; j++) ssum += expf(o[j] - m);
        float l = logf(ssum);
        for (int j = 0; j < 10; j++) out[g * 10 + j] = o[j] - m - l;
    }
}

extern "C" void kernel_launch(void* const* d_in, const int* in_sizes, int n_in,
                              void* d_out, int out_size, void* d_ws, size_t ws_size,
                              hipStream_t stream) {
    const float* x    = (const float*)d_in[0];
    const int*   ei   = (const int*)d_in[1];
    const int*   batch= (const int*)d_in[2];
    const float* W1   = (const float*)d_in[3];
    const float* b1   = (const float*)d_in[4];
    const float* W2   = (const float*)d_in[5];
    const float* b2   = (const float*)d_in[6];
    const float* fc1W = (const float*)d_in[7];
    const float* fc1b = (const float*)d_in[8];
    const float* fc2W = (const float*)d_in[9];
    const float* fc2b = (const float*)d_in[10];
    float* out = (float*)d_out;

    int N = in_sizes[0] / DH;     // 100000
    int E = in_sizes[1] / 2;      // 1600000
    int G = out_size / 10;        // 64

    char* p = (char*)d_ws;
    auto alloc = [&](size_t bytes) {
        char* r = p;
        p += (bytes + 255) & ~(size_t)255;
        return r;
    };
    unsigned short* hs = (unsigned short*)alloc((size_t)N * DH * 2);  // bf16 hidden
    unsigned short* a1 = (unsigned short*)alloc((size_t)N * DH * 2);  // bf16 act (both layers)
    int*   csr  = (int*)alloc((size_t)E * 4);
    int*   off  = (int*)alloc((size_t)(N + 1) * 4);
    float* dinv = (float*)alloc((size_t)N * 4);
    int nbuck = (N + 511) >> 9;   // 196
    unsigned int* pairs = (unsigned int*)alloc((size_t)nbuck * BCAP * 4);
    unsigned short* Wt1 = (unsigned short*)alloc(DH * DH * 2);
    unsigned short* Wt2 = (unsigned short*)alloc(DH * DH * 2);
    // zero-init region: Gsum (32KB) + bcur (16KB) contiguous -> one memset
    float* Gsum = (float*)alloc((size_t)G * DH * 4);
    int*   bcur = (int*)alloc(256 * 16 * 4);
    int*   cnts = (int*)alloc((size_t)G * 4);

    const int* row = ei;       // message source
    const int* col = ei + E;   // aggregation target

    hipMemsetAsync(Gsum, 0, (size_t)G * DH * 4 + 256 * 16 * 4, stream);

    const int chunk = 8192;
    int ablocks = (E + chunk - 1) / chunk;  // 196
    k_bucket<<<ablocks, 256, 0, stream>>>(row, col, E, nbuck, chunk, pairs, bcur);
    k_build<<<nbuck, 256, 0, stream>>>(pairs, bcur, nbuck, N, off, dinv, csr);
    k_prepW<<<128, 256, 0, stream>>>(W1, W2, Wt1, Wt2);

    int gblocks = (N + 63) / 64;
    int ablk = (N + 3) / 4;
    // layer 1
    k_gemm_mfma<<<gblocks, 256, 0, stream>>>(x, 0, Wt1, dinv, hs, N);
    k_agg<<<ablk, 256, 0, stream>>>((const unsigned int*)hs, (unsigned int*)a1,
                                    dinv, off, csr, b1, 1, N);
    // layer 2
    k_gemm_mfma<<<gblocks, 256, 0, stream>>>(a1, 1, Wt2, dinv, hs, N);
    k_agg<<<ablk, 256, 0, stream>>>((const unsigned int*)hs, (unsigned int*)a1,
                                    dinv, off, csr, b2, 0, N);

    dim3 pg(G, 8);
    k_pool<<<pg, DH, 0, stream>>>(a1, batch, Gsum, cnts, N);
    k_head<<<G, 64, 0, stream>>>(Gsum, cnts, fc1W, fc1b, fc2W, fc2b, out);
}

// Round 5
// 355.604 us; speedup vs baseline: 1.6962x; 1.1482x over previous
//
#include <hip/hip_runtime.h>
#include <math.h>

#define DH 128
#define BCAP 16384  // slots per 512-node bucket (mean ~8163, >20 sigma headroom)

typedef __bf16 bf8_t __attribute__((ext_vector_type(8)));
typedef short short8 __attribute__((ext_vector_type(8)));
typedef float f4_t __attribute__((ext_vector_type(4)));

__device__ inline unsigned short f2b(float f) {
    unsigned int u = __builtin_bit_cast(unsigned int, f);
    u = u + 0x7fffu + ((u >> 16) & 1u);  // RNE
    return (unsigned short)(u >> 16);
}
__device__ inline float b2f(unsigned short h) {
    return __builtin_bit_cast(float, (unsigned int)h << 16);
}

// ---------- Pass A: bucket edges by dst>>9 ----------
__global__ __launch_bounds__(256) void k_bucket(const int* __restrict__ row,
                                                const int* __restrict__ col,
                                                int E, int nbuck, int chunk,
                                                unsigned int* __restrict__ pairs,
                                                int* __restrict__ bcur) {
    __shared__ int lcnt[256];
    __shared__ int lbase[256];
    __shared__ unsigned int srec[8192];
    int t = threadIdx.x;
    int e0 = blockIdx.x * chunk;
    int e1 = min(e0 + chunk, E);
    lcnt[t] = 0;
    __syncthreads();
    for (int i = e0 + t; i < e1; i += 256) {
        int d = col[i];
        int b = d >> 9;
        int slot = atomicAdd(&lcnt[b], 1);
        srec[i - e0] = ((unsigned int)b << 22) | ((unsigned int)(d & 511) << 13)
                     | (unsigned int)slot;
    }
    __syncthreads();
    if (t < nbuck) {
        int c = lcnt[t];
        lbase[t] = (c > 0) ? atomicAdd(&bcur[t * 16], c) : 0;  // stride 16: 1 line/counter
    }
    __syncthreads();
    for (int i = e0 + t; i < e1; i += 256) {
        unsigned int r = srec[i - e0];
        int b = r >> 22;
        unsigned int dl = (r >> 13) & 511u;
        int slot = (int)(r & 8191u);
        int g = lbase[b] + slot;
        if (g < BCAP)
            pairs[(size_t)b * BCAP + g] = ((unsigned int)row[i] << 9) | dl;
    }
}

// ---------- Pass B: one block per bucket builds off/dinv/csr (LDS-local) ----------
__global__ __launch_bounds__(256) void k_build(const unsigned int* __restrict__ pairs,
                                               const int* __restrict__ bcur,
                                               int nbuck, int N,
                                               int* __restrict__ off,
                                               float* __restrict__ dinv,
                                               int* __restrict__ csr) {
    __shared__ int sb[256];
    __shared__ int cnt2[512];
    __shared__ int excl[512];
    __shared__ int curi[512];
    __shared__ int stmp[256];
    int b = blockIdx.x, t = threadIdx.x;
    sb[t] = (t < nbuck) ? min(bcur[t * 16], BCAP) : 0;
    __syncthreads();
    for (int d = 1; d < 256; d <<= 1) {
        int v = (t >= d) ? sb[t - d] : 0;
        __syncthreads();
        sb[t] += v;
        __syncthreads();
    }
    int base = (b == 0) ? 0 : sb[b - 1];
    int cnt = sb[b] - base;
    int node0 = b << 9;
    int nodes = min(512, N - node0);
    cnt2[t] = 0; cnt2[t + 256] = 0;
    __syncthreads();
    const unsigned int* pp = pairs + (size_t)b * BCAP;
    for (int i = t; i < cnt; i += 256)
        atomicAdd(&cnt2[pp[i] & 511u], 1);
    __syncthreads();
    stmp[t] = cnt2[2 * t] + cnt2[2 * t + 1];
    __syncthreads();
    for (int d = 1; d < 256; d <<= 1) {
        int v = (t >= d) ? stmp[t - d] : 0;
        __syncthreads();
        stmp[t] += v;
        __syncthreads();
    }
    int pre = (t == 0) ? 0 : stmp[t - 1];
    excl[2 * t] = pre;
    excl[2 * t + 1] = pre + cnt2[2 * t];
    __syncthreads();
    if (t < nodes) {
        off[node0 + t] = base + excl[t];
        dinv[node0 + t] = rsqrtf((float)(cnt2[t] + 1));
    }
    int t2 = t + 256;
    if (t2 < nodes) {
        off[node0 + t2] = base + excl[t2];
        dinv[node0 + t2] = rsqrtf((float)(cnt2[t2] + 1));
    }
    if (t == 0) off[node0 + nodes] = base + cnt;
    curi[t] = excl[t]; curi[t + 256] = excl[t + 256];
    __syncthreads();
    for (int i = t; i < cnt; i += 256) {
        unsigned int p = pp[i];
        int d = (int)(p & 511u);
        int slot = atomicAdd(&curi[d], 1);
        csr[base + slot] = (int)(p >> 9);
    }
}

// ---------- W prep (both layers): Wt[n][k] = bf16(W[k][n]) ----------
__global__ void k_prepW(const float* __restrict__ W1, const float* __restrict__ W2,
                        unsigned short* __restrict__ Wt1, unsigned short* __restrict__ Wt2) {
    int t = blockIdx.x * blockDim.x + threadIdx.x;  // 32768
    const float* W = (t < 16384) ? W1 : W2;
    unsigned short* Wt = (t < 16384) ? Wt1 : Wt2;
    int v = t & 16383;
    int k = v >> 7, n = v & 127;
    Wt[n * DH + k] = f2b(W[k * DH + n]);
}

// ---------- MFMA GEMM: Y[r][c] = bf16( (X[r]@W)[c] * dinv[r] ) ----------
__global__ __launch_bounds__(256) void k_gemm_mfma(const void* __restrict__ Xin, int x_is_bf16,
                                                   const unsigned short* __restrict__ Wt,
                                                   const float* __restrict__ dinv,
                                                   unsigned short* __restrict__ Y, int nrows) {
    __shared__ unsigned short Xs[64 * 136];
    __shared__ unsigned short Ws[128 * 136];
    int t = threadIdx.x;
    int row0 = blockIdx.x * 64;

    for (int v = t; v < 128 * 32; v += 256) {
        int n = v >> 5, kq = v & 31;
        ushort4 w = ((const ushort4*)Wt)[v];
        *(ushort4*)&Ws[n * 136 + kq * 4] = w;
    }
    if (x_is_bf16) {
        const unsigned short* X = (const unsigned short*)Xin;
        for (int v = t; v < 64 * 32; v += 256) {
            int r = v >> 5, cq = v & 31;
            int gr = row0 + r;
            ushort4 h;
            if (gr < nrows) h = ((const ushort4*)X)[(size_t)gr * 32 + cq];
            else { h.x = 0; h.y = 0; h.z = 0; h.w = 0; }
            *(ushort4*)&Xs[r * 136 + cq * 4] = h;
        }
    } else {
        const float* X = (const float*)Xin;
        for (int v = t; v < 64 * 32; v += 256) {
            int r = v >> 5, cq = v & 31;
            int gr = row0 + r;
            ushort4 h;
            if (gr < nrows) {
                float4 xv = ((const float4*)X)[(size_t)gr * 32 + cq];
                h.x = f2b(xv.x); h.y = f2b(xv.y); h.z = f2b(xv.z); h.w = f2b(xv.w);
            } else { h.x = 0; h.y = 0; h.z = 0; h.w = 0; }
            *(ushort4*)&Xs[r * 136 + cq * 4] = h;
        }
    }
    __syncthreads();

    int w = t >> 6;
    int lane = t & 63;
    int quad = lane >> 4;
    int l16 = lane & 15;
    int rw = w * 16;

    f4_t acc[8];
#pragma unroll
    for (int j = 0; j < 8; j++) acc[j] = (f4_t){0.f, 0.f, 0.f, 0.f};

#pragma unroll
    for (int kk = 0; kk < 4; kk++) {
        int k0 = kk * 32;
        bf8_t a = __builtin_bit_cast(bf8_t,
            *(const short8*)&Xs[(rw + l16) * 136 + k0 + quad * 8]);
#pragma unroll
        for (int j = 0; j < 8; j++) {
            bf8_t b = __builtin_bit_cast(bf8_t,
                *(const short8*)&Ws[(j * 16 + l16) * 136 + k0 + quad * 8]);
            acc[j] = __builtin_amdgcn_mfma_f32_16x16x32_bf16(a, b, acc[j], 0, 0, 0);
        }
    }

#pragma unroll
    for (int reg = 0; reg < 4; reg++) {
        int r = row0 + rw + quad * 4 + reg;
        if (r < nrows) {
            float dv = dinv[r];
#pragma unroll
            for (int j = 0; j < 8; j++) {
                float val = acc[j][reg] * dv;
                Y[(size_t)r * DH + j * 16 + l16] = f2b(val);
            }
        }
    }
}

// ---------- Aggregation: wave-per-node, full-row u32 gathers, 8-deep MLP ----------
__global__ __launch_bounds__(256) void k_agg(const unsigned int* __restrict__ Hs32,
                                             unsigned int* __restrict__ Out32,
                                             const float* __restrict__ dinv,
                                             const int* __restrict__ off,
                                             const int* __restrict__ csr,
                                             const float* __restrict__ bias,
                                             int elu, int N) {
    int wv = __builtin_amdgcn_readfirstlane((int)(threadIdx.x >> 6));
    int n = blockIdx.x * 4 + wv;
    if (n >= N) return;
    int l = threadIdx.x & 63;
    int s = off[n], e = off[n + 1];
    unsigned int u = Hs32[(size_t)n * 64 + l];  // self loop
    float a0 = b2f((unsigned short)(u & 0xffffu));
    float a1 = b2f((unsigned short)(u >> 16));
    int i = s;
    while (i + 8 <= e) {
        int j0 = csr[i], j1 = csr[i + 1], j2 = csr[i + 2], j3 = csr[i + 3];
        int j4 = csr[i + 4], j5 = csr[i + 5], j6 = csr[i + 6], j7 = csr[i + 7];
        unsigned int v0 = Hs32[(size_t)j0 * 64 + l];
        unsigned int v1 = Hs32[(size_t)j1 * 64 + l];
        unsigned int v2 = Hs32[(size_t)j2 * 64 + l];
        unsigned int v3 = Hs32[(size_t)j3 * 64 + l];
        unsigned int v4 = Hs32[(size_t)j4 * 64 + l];
        unsigned int v5 = Hs32[(size_t)j5 * 64 + l];
        unsigned int v6 = Hs32[(size_t)j6 * 64 + l];
        unsigned int v7 = Hs32[(size_t)j7 * 64 + l];
        a0 += b2f((unsigned short)(v0 & 0xffffu)) + b2f((unsigned short)(v1 & 0xffffu))
            + b2f((unsigned short)(v2 & 0xffffu)) + b2f((unsigned short)(v3 & 0xffffu))
            + b2f((unsigned short)(v4 & 0xffffu)) + b2f((unsigned short)(v5 & 0xffffu))
            + b2f((unsigned short)(v6 & 0xffffu)) + b2f((unsigned short)(v7 & 0xffffu));
        a1 += b2f((unsigned short)(v0 >> 16)) + b2f((unsigned short)(v1 >> 16))
            + b2f((unsigned short)(v2 >> 16)) + b2f((unsigned short)(v3 >> 16))
            + b2f((unsigned short)(v4 >> 16)) + b2f((unsigned short)(v5 >> 16))
            + b2f((unsigned short)(v6 >> 16)) + b2f((unsigned short)(v7 >> 16));
        i += 8;
    }
    for (; i < e; i++) {
        int j = csr[i];
        unsigned int v = Hs32[(size_t)j * 64 + l];
        a0 += b2f((unsigned short)(v & 0xffffu));
        a1 += b2f((unsigned short)(v >> 16));
    }
    float2 bb = ((const float2*)bias)[l];
    float dv = dinv[n];
    float o0 = a0 * dv + bb.x;
    float o1 = a1 * dv + bb.y;
    if (elu) {
        o0 = o0 > 0.f ? o0 : expm1f(o0);
        o1 = o1 > 0.f ? o1 : expm1f(o1);
    }
    Out32[(size_t)n * 64 + l] = (unsigned int)f2b(o0) | ((unsigned int)f2b(o1) << 16);
}

// ---------- Mean pool v2: wave-per-row streaming, (G x 32) blocks ----------
__global__ __launch_bounds__(256) void k_pool(const unsigned int* __restrict__ H32,
                                              const int* __restrict__ batch,
                                              float* __restrict__ Gsum,
                                              int* __restrict__ cnts, int N) {
    int g = blockIdx.x;
    int p = blockIdx.y;
    int t = threadIdx.x;
    int lane = t & 63;
    int rg = t >> 6;  // wave 0..3
    int lo = 0, hi = N;
    while (lo < hi) { int m = (lo + hi) >> 1; if (batch[m] < g) lo = m + 1; else hi = m; }
    int s = lo;
    hi = N;
    while (lo < hi) { int m = (lo + hi) >> 1; if (batch[m] < g + 1) lo = m + 1; else hi = m; }
    int e = lo;
    int len = e - s;
    int parts = (int)gridDim.y;
    int chunk = (len + parts - 1) / parts;
    int i0 = s + p * chunk;
    int i1 = min(i0 + chunk, e);
    float a0 = 0.f, a1 = 0.f;
    for (int i = i0 + rg; i < i1; i += 4) {  // one full 256B row per wave per iter
        unsigned int v = H32[(size_t)i * 64 + lane];
        a0 += b2f((unsigned short)(v & 0xffffu));
        a1 += b2f((unsigned short)(v >> 16));
    }
    __shared__ float ps[4][DH];
    ps[rg][lane * 2] = a0;
    ps[rg][lane * 2 + 1] = a1;
    __syncthreads();
    if (t < DH) {
        float v = ps[0][t] + ps[1][t] + ps[2][t] + ps[3][t];
        atomicAdd(&Gsum[g * DH + t], v);
    }
    if (p == 0 && t == 0) cnts[g] = len;
}

// ---------- MLP head + log_softmax ----------
__global__ __launch_bounds__(64) void k_head(const float* __restrict__ Gsum,
                                             const int* __restrict__ cnts,
                                             const float* __restrict__ W1,
                                             const float* __restrict__ b1,
                                             const float* __restrict__ W2,
                                             const float* __restrict__ b2,
                                             float* __restrict__ out) {
    int g = blockIdx.x;
    int t = threadIdx.x;
    __shared__ float gv[DH];
    __shared__ float mid[20];
    __shared__ float o[10];
    float inv = 1.f / fmaxf((float)cnts[g], 1.f);
    for (int i = t; i < DH; i += 64) gv[i] = Gsum[g * DH + i] * inv;
    __syncthreads();
    if (t < 20) {
        float a = b1[t];
        for (int k = 0; k < DH; k++) a += gv[k] * W1[k * 20 + t];
        mid[t] = fmaxf(a, 0.f);
    }
    __syncthreads();
    if (t < 10) {
        float a = b2[t];
        for (int k = 0; k < 20; k++) a += mid[k] * W2[k * 10 + t];
        o[t] = a;
    }
    __syncthreads();
    if (t == 0) {
        float m = -1e30f;
        for (int j = 0; j < 10; j++) m = fmaxf(m, o[j]);
        float ssum = 0.f;
        for (int j = 0; j < 10; j++) ssum += expf(o[j] - m);
        float l = logf(ssum);
        for (int j = 0; j < 10; j++) out[g * 10 + j] = o[j] - m - l;
    }
}

extern "C" void kernel_launch(void* const* d_in, const int* in_sizes, int n_in,
                              void* d_out, int out_size, void* d_ws, size_t ws_size,
                              hipStream_t stream) {
    const float* x    = (const float*)d_in[0];
    const int*   ei   = (const int*)d_in[1];
    const int*   batch= (const int*)d_in[2];
    const float* W1   = (const float*)d_in[3];
    const float* b1   = (const float*)d_in[4];
    const float* W2   = (const float*)d_in[5];
    const float* b2   = (const float*)d_in[6];
    const float* fc1W = (const float*)d_in[7];
    const float* fc1b = (const float*)d_in[8];
    const float* fc2W = (const float*)d_in[9];
    const float* fc2b = (const float*)d_in[10];
    float* out = (float*)d_out;

    int N = in_sizes[0] / DH;     // 100000
    int E = in_sizes[1] / 2;      // 1600000
    int G = out_size / 10;        // 64

    char* p = (char*)d_ws;
    auto alloc = [&](size_t bytes) {
        char* r = p;
        p += (bytes + 255) & ~(size_t)255;
        return r;
    };
    unsigned short* hs = (unsigned short*)alloc((size_t)N * DH * 2);  // bf16 hidden
    unsigned short* a1 = (unsigned short*)alloc((size_t)N * DH * 2);  // bf16 act (both layers)
    int*   csr  = (int*)alloc((size_t)E * 4);
    int*   off  = (int*)alloc((size_t)(N + 1) * 4);
    float* dinv = (float*)alloc((size_t)N * 4);
    int nbuck = (N + 511) >> 9;   // 196
    unsigned int* pairs = (unsigned int*)alloc((size_t)nbuck * BCAP * 4);
    unsigned short* Wt1 = (unsigned short*)alloc(DH * DH * 2);
    unsigned short* Wt2 = (unsigned short*)alloc(DH * DH * 2);
    float* Gsum = (float*)alloc((size_t)G * DH * 4);
    int*   bcur = (int*)alloc(256 * 16 * 4);
    int*   cnts = (int*)alloc((size_t)G * 4);

    const int* row = ei;       // message source
    const int* col = ei + E;   // aggregation target

    hipMemsetAsync(Gsum, 0, (size_t)G * DH * 4 + 256 * 16 * 4, stream);

    const int chunk = 8192;
    int ablocks = (E + chunk - 1) / chunk;  // 196
    k_bucket<<<ablocks, 256, 0, stream>>>(row, col, E, nbuck, chunk, pairs, bcur);
    k_build<<<nbuck, 256, 0, stream>>>(pairs, bcur, nbuck, N, off, dinv, csr);
    k_prepW<<<128, 256, 0, stream>>>(W1, W2, Wt1, Wt2);

    int gblocks = (N + 63) / 64;
    int ablk = (N + 3) / 4;
    // layer 1
    k_gemm_mfma<<<gblocks, 256, 0, stream>>>(x, 0, Wt1, dinv, hs, N);
    k_agg<<<ablk, 256, 0, stream>>>((const unsigned int*)hs, (unsigned int*)a1,
                                    dinv, off, csr, b1, 1, N);
    // layer 2
    k_gemm_mfma<<<gblocks, 256, 0, stream>>>(a1, 1, Wt2, dinv, hs, N);
    k_agg<<<ablk, 256, 0, stream>>>((const unsigned int*)hs, (unsigned int*)a1,
                                    dinv, off, csr, b2, 0, N);

    dim3 pg(G, 32);
    k_pool<<<pg, 256, 0, stream>>>((const unsigned int*)a1, batch, Gsum, cnts, N);
    k_head<<<G, 64, 0, stream>>>(Gsum, cnts, fc1W, fc1b, fc2W, fc2b, out);
}

// Round 6
// 333.123 us; speedup vs baseline: 1.8106x; 1.0675x over previous
//
#include <hip/hip_runtime.h>
#include <math.h>

#define DH 128
#define BCAP 16384  // slots per 512-node bucket (mean ~8163, >20 sigma headroom)

typedef __bf16 bf8_t __attribute__((ext_vector_type(8)));
typedef short short8 __attribute__((ext_vector_type(8)));
typedef float f4_t __attribute__((ext_vector_type(4)));
typedef float f2_t __attribute__((ext_vector_type(2)));

__device__ inline unsigned short f2b(float f) {
    unsigned int u = __builtin_bit_cast(unsigned int, f);
    u = u + 0x7fffu + ((u >> 16) & 1u);  // RNE
    return (unsigned short)(u >> 16);
}
__device__ inline float b2f(unsigned short h) {
    return __builtin_bit_cast(float, (unsigned int)h << 16);
}

// ---------- Pass A: bucket edges by dst>>9 ----------
__global__ __launch_bounds__(256) void k_bucket(const int* __restrict__ row,
                                                const int* __restrict__ col,
                                                int E, int nbuck, int chunk,
                                                unsigned int* __restrict__ pairs,
                                                int* __restrict__ bcur) {
    __shared__ int lcnt[256];
    __shared__ int lbase[256];
    __shared__ unsigned int srec[8192];
    int t = threadIdx.x;
    int e0 = blockIdx.x * chunk;
    int e1 = min(e0 + chunk, E);
    lcnt[t] = 0;
    __syncthreads();
    for (int i = e0 + t; i < e1; i += 256) {
        int d = col[i];
        int b = d >> 9;
        int slot = atomicAdd(&lcnt[b], 1);
        srec[i - e0] = ((unsigned int)b << 22) | ((unsigned int)(d & 511) << 13)
                     | (unsigned int)slot;
    }
    __syncthreads();
    if (t < nbuck) {
        int c = lcnt[t];
        lbase[t] = (c > 0) ? atomicAdd(&bcur[t * 16], c) : 0;  // stride 16: 1 line/counter
    }
    __syncthreads();
    for (int i = e0 + t; i < e1; i += 256) {
        unsigned int r = srec[i - e0];
        int b = r >> 22;
        unsigned int dl = (r >> 13) & 511u;
        int slot = (int)(r & 8191u);
        int g = lbase[b] + slot;
        if (g < BCAP)
            pairs[(size_t)b * BCAP + g] = ((unsigned int)row[i] << 9) | dl;
    }
}

// ---------- Pass B: one block per bucket builds off/dinv/csr (LDS-local) ----------
__global__ __launch_bounds__(256) void k_build(const unsigned int* __restrict__ pairs,
                                               const int* __restrict__ bcur,
                                               int nbuck, int N,
                                               int* __restrict__ off,
                                               float* __restrict__ dinv,
                                               int* __restrict__ csr) {
    __shared__ int sb[256];
    __shared__ int cnt2[512];
    __shared__ int excl[512];
    __shared__ int curi[512];
    __shared__ int stmp[256];
    int b = blockIdx.x, t = threadIdx.x;
    sb[t] = (t < nbuck) ? min(bcur[t * 16], BCAP) : 0;
    __syncthreads();
    for (int d = 1; d < 256; d <<= 1) {
        int v = (t >= d) ? sb[t - d] : 0;
        __syncthreads();
        sb[t] += v;
        __syncthreads();
    }
    int base = (b == 0) ? 0 : sb[b - 1];
    int cnt = sb[b] - base;
    int node0 = b << 9;
    int nodes = min(512, N - node0);
    cnt2[t] = 0; cnt2[t + 256] = 0;
    __syncthreads();
    const unsigned int* pp = pairs + (size_t)b * BCAP;
    for (int i = t; i < cnt; i += 256)
        atomicAdd(&cnt2[pp[i] & 511u], 1);
    __syncthreads();
    stmp[t] = cnt2[2 * t] + cnt2[2 * t + 1];
    __syncthreads();
    for (int d = 1; d < 256; d <<= 1) {
        int v = (t >= d) ? stmp[t - d] : 0;
        __syncthreads();
        stmp[t] += v;
        __syncthreads();
    }
    int pre = (t == 0) ? 0 : stmp[t - 1];
    excl[2 * t] = pre;
    excl[2 * t + 1] = pre + cnt2[2 * t];
    __syncthreads();
    if (t < nodes) {
        off[node0 + t] = base + excl[t];
        dinv[node0 + t] = rsqrtf((float)(cnt2[t] + 1));
    }
    int t2 = t + 256;
    if (t2 < nodes) {
        off[node0 + t2] = base + excl[t2];
        dinv[node0 + t2] = rsqrtf((float)(cnt2[t2] + 1));
    }
    if (t == 0) off[node0 + nodes] = base + cnt;
    curi[t] = excl[t]; curi[t + 256] = excl[t + 256];
    __syncthreads();
    for (int i = t; i < cnt; i += 256) {
        unsigned int p = pp[i];
        int d = (int)(p & 511u);
        int slot = atomicAdd(&curi[d], 1);
        csr[base + slot] = (int)(p >> 9);
    }
}

// ---------- W prep (both layers): Wt[n][k] = bf16(W[k][n]) ----------
__global__ void k_prepW(const float* __restrict__ W1, const float* __restrict__ W2,
                        unsigned short* __restrict__ Wt1, unsigned short* __restrict__ Wt2) {
    int t = blockIdx.x * blockDim.x + threadIdx.x;  // 32768
    const float* W = (t < 16384) ? W1 : W2;
    unsigned short* Wt = (t < 16384) ? Wt1 : Wt2;
    int v = t & 16383;
    int k = v >> 7, n = v & 127;
    Wt[n * DH + k] = f2b(W[k * DH + n]);
}

// ---------- MFMA GEMM -> fp8 e4m3 table, lane-major permuted rows ----------
// Row r byte p = l16*8 + j holds col j*16+l16 of (X[r]@W)*dinv[r].
__global__ __launch_bounds__(256) void k_gemm_mfma(const void* __restrict__ Xin, int x_is_bf16,
                                                   const unsigned short* __restrict__ Wt,
                                                   const float* __restrict__ dinv,
                                                   unsigned char* __restrict__ Y, int nrows) {
    __shared__ unsigned short Xs[64 * 136];
    __shared__ unsigned short Ws[128 * 136];
    int t = threadIdx.x;
    int row0 = blockIdx.x * 64;

    for (int v = t; v < 128 * 32; v += 256) {
        int n = v >> 5, kq = v & 31;
        ushort4 w = ((const ushort4*)Wt)[v];
        *(ushort4*)&Ws[n * 136 + kq * 4] = w;
    }
    if (x_is_bf16) {
        const unsigned short* X = (const unsigned short*)Xin;
        for (int v = t; v < 64 * 32; v += 256) {
            int r = v >> 5, cq = v & 31;
            int gr = row0 + r;
            ushort4 h;
            if (gr < nrows) h = ((const ushort4*)X)[(size_t)gr * 32 + cq];
            else { h.x = 0; h.y = 0; h.z = 0; h.w = 0; }
            *(ushort4*)&Xs[r * 136 + cq * 4] = h;
        }
    } else {
        const float* X = (const float*)Xin;
        for (int v = t; v < 64 * 32; v += 256) {
            int r = v >> 5, cq = v & 31;
            int gr = row0 + r;
            ushort4 h;
            if (gr < nrows) {
                float4 xv = ((const float4*)X)[(size_t)gr * 32 + cq];
                h.x = f2b(xv.x); h.y = f2b(xv.y); h.z = f2b(xv.z); h.w = f2b(xv.w);
            } else { h.x = 0; h.y = 0; h.z = 0; h.w = 0; }
            *(ushort4*)&Xs[r * 136 + cq * 4] = h;
        }
    }
    __syncthreads();

    int w = t >> 6;
    int lane = t & 63;
    int quad = lane >> 4;
    int l16 = lane & 15;
    int rw = w * 16;

    f4_t acc[8];
#pragma unroll
    for (int j = 0; j < 8; j++) acc[j] = (f4_t){0.f, 0.f, 0.f, 0.f};

#pragma unroll
    for (int kk = 0; kk < 4; kk++) {
        int k0 = kk * 32;
        bf8_t a = __builtin_bit_cast(bf8_t,
            *(const short8*)&Xs[(rw + l16) * 136 + k0 + quad * 8]);
#pragma unroll
        for (int j = 0; j < 8; j++) {
            bf8_t b = __builtin_bit_cast(bf8_t,
                *(const short8*)&Ws[(j * 16 + l16) * 136 + k0 + quad * 8]);
            acc[j] = __builtin_amdgcn_mfma_f32_16x16x32_bf16(a, b, acc[j], 0, 0, 0);
        }
    }

#pragma unroll
    for (int reg = 0; reg < 4; reg++) {
        int r = row0 + rw + quad * 4 + reg;
        if (r < nrows) {
            float dv = dinv[r];
            float v0 = acc[0][reg] * dv, v1 = acc[1][reg] * dv;
            float v2 = acc[2][reg] * dv, v3 = acc[3][reg] * dv;
            float v4 = acc[4][reg] * dv, v5 = acc[5][reg] * dv;
            float v6 = acc[6][reg] * dv, v7 = acc[7][reg] * dv;
            int d0 = __builtin_amdgcn_cvt_pk_fp8_f32(v0, v1, 0, false);
            d0 = __builtin_amdgcn_cvt_pk_fp8_f32(v2, v3, d0, true);
            int d1 = __builtin_amdgcn_cvt_pk_fp8_f32(v4, v5, 0, false);
            d1 = __builtin_amdgcn_cvt_pk_fp8_f32(v6, v7, d1, true);
            *(uint2*)&Y[(size_t)r * DH + l16 * 8] = make_uint2((unsigned)d0, (unsigned)d1);
        }
    }
}

// ---------- Aggregation: wave-per-node, half-wave per fp8 row (128B), 4 slots deep ----
// Permuted byte p (lane l<32 holds p=4l..4l+3) -> col = (p&7)*16 + (p>>3).
__global__ __launch_bounds__(256) void k_agg(const unsigned int* __restrict__ T,
                                             unsigned short* __restrict__ Out,
                                             const float* __restrict__ dinv,
                                             const int* __restrict__ off,
                                             const int* __restrict__ csr,
                                             const float* __restrict__ bias,
                                             int elu, int N) {
    int wv = threadIdx.x >> 6;
    int n = blockIdx.x * 4 + wv;
    if (n >= N) return;
    int lane = threadIdx.x & 63;
    int h = lane >> 5;   // half-wave 0/1
    int l = lane & 31;   // dword within row
    int s = off[n], e = off[n + 1];

    float a0 = 0.f, a1 = 0.f, a2 = 0.f, a3 = 0.f;
    if (h == 0) {  // self loop
        unsigned int v = T[(size_t)n * 32 + l];
        f2_t lo = __builtin_amdgcn_cvt_pk_f32_fp8((int)v, false);
        f2_t hi = __builtin_amdgcn_cvt_pk_f32_fp8((int)v, true);
        a0 = lo.x; a1 = lo.y; a2 = hi.x; a3 = hi.y;
    }
    int i = s;
    for (; i + 8 <= e; i += 8) {  // 8 edges/iter: 2 per slot (half-waves) x 4 slots
        int j0 = csr[i + h], j1 = csr[i + 2 + h], j2 = csr[i + 4 + h], j3 = csr[i + 6 + h];
        unsigned int v0 = T[(size_t)j0 * 32 + l];
        unsigned int v1 = T[(size_t)j1 * 32 + l];
        unsigned int v2 = T[(size_t)j2 * 32 + l];
        unsigned int v3 = T[(size_t)j3 * 32 + l];
        f2_t lo0 = __builtin_amdgcn_cvt_pk_f32_fp8((int)v0, false);
        f2_t hi0 = __builtin_amdgcn_cvt_pk_f32_fp8((int)v0, true);
        f2_t lo1 = __builtin_amdgcn_cvt_pk_f32_fp8((int)v1, false);
        f2_t hi1 = __builtin_amdgcn_cvt_pk_f32_fp8((int)v1, true);
        f2_t lo2 = __builtin_amdgcn_cvt_pk_f32_fp8((int)v2, false);
        f2_t hi2 = __builtin_amdgcn_cvt_pk_f32_fp8((int)v2, true);
        f2_t lo3 = __builtin_amdgcn_cvt_pk_f32_fp8((int)v3, false);
        f2_t hi3 = __builtin_amdgcn_cvt_pk_f32_fp8((int)v3, true);
        a0 += lo0.x + lo1.x + lo2.x + lo3.x;
        a1 += lo0.y + lo1.y + lo2.y + lo3.y;
        a2 += hi0.x + hi1.x + hi2.x + hi3.x;
        a3 += hi0.y + hi1.y + hi2.y + hi3.y;
    }
    for (; i + 2 <= e; i += 2) {
        int j = csr[i + h];
        unsigned int v = T[(size_t)j * 32 + l];
        f2_t lo = __builtin_amdgcn_cvt_pk_f32_fp8((int)v, false);
        f2_t hi = __builtin_amdgcn_cvt_pk_f32_fp8((int)v, true);
        a0 += lo.x; a1 += lo.y; a2 += hi.x; a3 += hi.y;
    }
    if (i < e && h == 0) {  // odd tail edge
        int j = csr[i];
        unsigned int v = T[(size_t)j * 32 + l];
        f2_t lo = __builtin_amdgcn_cvt_pk_f32_fp8((int)v, false);
        f2_t hi = __builtin_amdgcn_cvt_pk_f32_fp8((int)v, true);
        a0 += lo.x; a1 += lo.y; a2 += hi.x; a3 += hi.y;
    }
    // fold half-wave B into A
    a0 += __shfl_down(a0, 32, 64);
    a1 += __shfl_down(a1, 32, 64);
    a2 += __shfl_down(a2, 32, 64);
    a3 += __shfl_down(a3, 32, 64);
    if (h == 0) {
        float dv = dinv[n];
        int p0 = 4 * l, p1 = p0 + 1, p2 = p0 + 2, p3 = p0 + 3;
        int c0 = ((p0 & 7) << 4) | (p0 >> 3);
        int c1 = ((p1 & 7) << 4) | (p1 >> 3);
        int c2 = ((p2 & 7) << 4) | (p2 >> 3);
        int c3 = ((p3 & 7) << 4) | (p3 >> 3);
        float o0 = a0 * dv + bias[c0];
        float o1 = a1 * dv + bias[c1];
        float o2 = a2 * dv + bias[c2];
        float o3 = a3 * dv + bias[c3];
        if (elu) {
            o0 = o0 > 0.f ? o0 : expm1f(o0);
            o1 = o1 > 0.f ? o1 : expm1f(o1);
            o2 = o2 > 0.f ? o2 : expm1f(o2);
            o3 = o3 > 0.f ? o3 : expm1f(o3);
        }
        size_t base = (size_t)n * DH;
        Out[base + c0] = f2b(o0);
        Out[base + c1] = f2b(o1);
        Out[base + c2] = f2b(o2);
        Out[base + c3] = f2b(o3);
    }
}

// ---------- Mean pool: wave-per-row streaming, (G x 32) blocks, bf16 input ----------
__global__ __launch_bounds__(256) void k_pool(const unsigned int* __restrict__ H32,
                                              const int* __restrict__ batch,
                                              float* __restrict__ Gsum,
                                              int* __restrict__ cnts, int N) {
    int g = blockIdx.x;
    int p = blockIdx.y;
    int t = threadIdx.x;
    int lane = t & 63;
    int rg = t >> 6;  // wave 0..3
    int lo = 0, hi = N;
    while (lo < hi) { int m = (lo + hi) >> 1; if (batch[m] < g) lo = m + 1; else hi = m; }
    int s = lo;
    hi = N;
    while (lo < hi) { int m = (lo + hi) >> 1; if (batch[m] < g + 1) lo = m + 1; else hi = m; }
    int e = lo;
    int len = e - s;
    int parts = (int)gridDim.y;
    int chunk = (len + parts - 1) / parts;
    int i0 = s + p * chunk;
    int i1 = min(i0 + chunk, e);
    float a0 = 0.f, a1 = 0.f;
    for (int i = i0 + rg; i < i1; i += 4) {
        unsigned int v = H32[(size_t)i * 64 + lane];
        a0 += b2f((unsigned short)(v & 0xffffu));
        a1 += b2f((unsigned short)(v >> 16));
    }
    __shared__ float ps[4][DH];
    ps[rg][lane * 2] = a0;
    ps[rg][lane * 2 + 1] = a1;
    __syncthreads();
    if (t < DH) {
        float v = ps[0][t] + ps[1][t] + ps[2][t] + ps[3][t];
        atomicAdd(&Gsum[g * DH + t], v);
    }
    if (p == 0 && t == 0) cnts[g] = len;
}

// ---------- MLP head + log_softmax ----------
__global__ __launch_bounds__(64) void k_head(const float* __restrict__ Gsum,
                                             const int* __restrict__ cnts,
                                             const float* __restrict__ W1,
                                             const float* __restrict__ b1,
                                             const float* __restrict__ W2,
                                             const float* __restrict__ b2,
                                             float* __restrict__ out) {
    int g = blockIdx.x;
    int t = threadIdx.x;
    __shared__ float gv[DH];
    __shared__ float mid[20];
    __shared__ float o[10];
    float inv = 1.f / fmaxf((float)cnts[g], 1.f);
    for (int i = t; i < DH; i += 64) gv[i] = Gsum[g * DH + i] * inv;
    __syncthreads();
    if (t < 20) {
        float a = b1[t];
        for (int k = 0; k < DH; k++) a += gv[k] * W1[k * 20 + t];
        mid[t] = fmaxf(a, 0.f);
    }
    __syncthreads();
    if (t < 10) {
        float a = b2[t];
        for (int k = 0; k < 20; k++) a += mid[k] * W2[k * 10 + t];
        o[t] = a;
    }
    __syncthreads();
    if (t == 0) {
        float m = -1e30f;
        for (int j = 0; j < 10; j++) m = fmaxf(m, o[j]);
        float ssum = 0.f;
        for (int j = 0; j < 10; j++) ssum += expf(o[j] - m);
        float l = logf(ssum);
        for (int j = 0; j < 10; j++) out[g * 10 + j] = o[j] - m - l;
    }
}

extern "C" void kernel_launch(void* const* d_in, const int* in_sizes, int n_in,
                              void* d_out, int out_size, void* d_ws, size_t ws_size,
                              hipStream_t stream) {
    const float* x    = (const float*)d_in[0];
    const int*   ei   = (const int*)d_in[1];
    const int*   batch= (const int*)d_in[2];
    const float* W1   = (const float*)d_in[3];
    const float* b1   = (const float*)d_in[4];
    const float* W2   = (const float*)d_in[5];
    const float* b2   = (const float*)d_in[6];
    const float* fc1W = (const float*)d_in[7];
    const float* fc1b = (const float*)d_in[8];
    const float* fc2W = (const float*)d_in[9];
    const float* fc2b = (const float*)d_in[10];
    float* out = (float*)d_out;

    int N = in_sizes[0] / DH;     // 100000
    int E = in_sizes[1] / 2;      // 1600000
    int G = out_size / 10;        // 64

    char* p = (char*)d_ws;
    auto alloc = [&](size_t bytes) {
        char* r = p;
        p += (bytes + 255) & ~(size_t)255;
        return r;
    };
    unsigned char*  t8 = (unsigned char*)alloc((size_t)N * DH);      // fp8 hidden table
    unsigned short* a1 = (unsigned short*)alloc((size_t)N * DH * 2); // bf16 act (both layers)
    int*   csr  = (int*)alloc((size_t)E * 4);
    int*   off  = (int*)alloc((size_t)(N + 1) * 4);
    float* dinv = (float*)alloc((size_t)N * 4);
    int nbuck = (N + 511) >> 9;   // 196
    unsigned int* pairs = (unsigned int*)alloc((size_t)nbuck * BCAP * 4);
    unsigned short* Wt1 = (unsigned short*)alloc(DH * DH * 2);
    unsigned short* Wt2 = (unsigned short*)alloc(DH * DH * 2);
    float* Gsum = (float*)alloc((size_t)G * DH * 4);
    int*   bcur = (int*)alloc(256 * 16 * 4);
    int*   cnts = (int*)alloc((size_t)G * 4);

    const int* row = ei;       // message source
    const int* col = ei + E;   // aggregation target

    hipMemsetAsync(Gsum, 0, (size_t)G * DH * 4 + 256 * 16 * 4, stream);

    const int chunk = 8192;
    int ablocks = (E + chunk - 1) / chunk;  // 196
    k_bucket<<<ablocks, 256, 0, stream>>>(row, col, E, nbuck, chunk, pairs, bcur);
    k_build<<<nbuck, 256, 0, stream>>>(pairs, bcur, nbuck, N, off, dinv, csr);
    k_prepW<<<128, 256, 0, stream>>>(W1, W2, Wt1, Wt2);

    int gblocks = (N + 63) / 64;
    int ablk = (N + 3) / 4;
    // layer 1
    k_gemm_mfma<<<gblocks, 256, 0, stream>>>(x, 0, Wt1, dinv, t8, N);
    k_agg<<<ablk, 256, 0, stream>>>((const unsigned int*)t8, a1, dinv, off, csr, b1, 1, N);
    // layer 2
    k_gemm_mfma<<<gblocks, 256, 0, stream>>>(a1, 1, Wt2, dinv, t8, N);
    k_agg<<<ablk, 256, 0, stream>>>((const unsigned int*)t8, a1, dinv, off, csr, b2, 0, N);

    dim3 pg(G, 32);
    k_pool<<<pg, 256, 0, stream>>>((const unsigned int*)a1, batch, Gsum, cnts, N);
    k_head<<<G, 64, 0, stream>>>(Gsum, cnts, fc1W, fc1b, fc2W, fc2b, out);
}